// Round 4
// baseline (242.444 us; speedup 1.0000x reference)
//
#include <hip/hip_runtime.h>

// Node_GCN: out[n,j,h] = FF_f(x)[n,j,h] + sum_i edge[n,i,j] * FF_g(cat(x,x))[n,i,h]
// fp32 globals, bf16 MFMA internals (abs threshold 9.56 >> bf16 error ~2).
// N=8, m=2048, D_IN=64, H=128.
//
//   k_gx  : gxT[8][128][2048] bf16 = (relu(x@gw1'+b)@gw2+b)^T  (gw1' = gw1[:64]+gw1[64:])
//   k_main: out[n,j,h] = edge^T @ gx + self_MLP(x_j)   fused, pure store (no RMW)
//           512 blocks (2/CU), tile 32j x 128h, K=2048 in BK=64 steps,
//           DOUBLE-BUFFERED LDS (1 barrier/iter) + pair-packed edge transpose.

typedef __attribute__((ext_vector_type(8))) short bf16x8;
typedef __attribute__((ext_vector_type(8))) unsigned short u16x8;
typedef __attribute__((ext_vector_type(4))) unsigned short u16x4;
typedef __attribute__((ext_vector_type(4))) float f32x4;

static __device__ __forceinline__ unsigned short f2bf(float f) {
  union { float f; unsigned int i; } c; c.f = f;
  return (unsigned short)((c.i + 0x7fffu + ((c.i >> 16) & 1u)) >> 16);
}

// ---------------- k_gx: sender MLP, transposed bf16 store (64 rows/block, 4 waves) ----------------
__global__ __launch_bounds__(256) void k_gx(
    const float* __restrict__ x,
    const float* __restrict__ gw1,
    const float* __restrict__ gb1,
    const float* __restrict__ gw2,
    const float* __restrict__ gb2,
    unsigned short* __restrict__ gxT)
{
  __shared__ short xs[64 * 64];     // 8 KB
  __shared__ short w1T[128 * 64];   // 16 KB  folded gw1' transposed [n][k], k<64
  __shared__ short w2T[128 * 128];  // 32 KB  gw2T [n][k], k<128
  __shared__ short h2s[64 * 128];   // 16 KB

  const int t = threadIdx.x;
  const int R0 = blockIdx.x * 64;

  for (int idx = t; idx < 64 * 128; idx += 256) {
    int k = idx >> 7, n = idx & 127;  // gw1[k][n], fold cat(x,x): +gw1[k+64][n]
    float v = gw1[idx] + gw1[64 * 128 + idx];
    w1T[(n << 6) + (((k >> 3) ^ (n & 7)) << 3) + (k & 7)] = (short)f2bf(v);
  }
  for (int idx = t; idx < 128 * 128; idx += 256) {
    int k = idx >> 7, n = idx & 127;  // gw2[k][n]
    w2T[(n << 7) + (((k >> 3) ^ (n & 7)) << 3) + (k & 7)] = (short)f2bf(gw2[idx]);
  }
  for (int s = t; s < 64 * 16; s += 256) {
    int row = s >> 4, c4 = s & 15;
    f32x4 v = *(const f32x4*)(x + (size_t)(R0 + row) * 64 + c4 * 4);
    u16x4 pk;
#pragma unroll
    for (int r = 0; r < 4; ++r) pk[r] = f2bf(v[r]);
    *(u16x4*)(xs + (row << 6) + (((c4 >> 1) ^ (row & 7)) << 3) + ((c4 & 1) << 2)) = pk;
  }
  __syncthreads();

  const int w = t >> 6, l = t & 63;
  const int lr = l & 15, q = l >> 4;
  const int mrow = w * 16 + lr;

  bf16x8 a[2];
#pragma unroll
  for (int ks = 0; ks < 2; ++ks) {
    int c = ks * 4 + q;
    a[ks] = *(const bf16x8*)(xs + (mrow << 6) + ((c ^ (mrow & 7)) << 3));
  }

  f32x4 acc;
#pragma unroll
  for (int nf = 0; nf < 8; ++nf) {
    acc = (f32x4){0.f, 0.f, 0.f, 0.f};
#pragma unroll
    for (int ks = 0; ks < 2; ++ks) {
      int c = ks * 4 + q;
      int nr = nf * 16 + lr;
      bf16x8 b = *(const bf16x8*)(w1T + (nr << 6) + ((c ^ (nr & 7)) << 3));
      acc = __builtin_amdgcn_mfma_f32_16x16x32_bf16(a[ks], b, acc, 0, 0, 0);
    }
    float bias = gb1[nf * 16 + lr];
#pragma unroll
    for (int r = 0; r < 4; ++r) {
      float v = acc[r] + bias;
      v = v > 0.f ? v : 0.f;
      int row = w * 16 + q * 4 + r, n = nf * 16 + lr;
      h2s[(row << 7) + (((n >> 3) ^ (row & 7)) << 3) + (n & 7)] = (short)f2bf(v);
    }
  }
  __syncthreads();

  bf16x8 a2[4];
#pragma unroll
  for (int ks = 0; ks < 4; ++ks) {
    int c = ks * 4 + q;
    a2[ks] = *(const bf16x8*)(h2s + (mrow << 7) + ((c ^ (mrow & 7)) << 3));
  }
  const int batch = R0 >> 11;
  const int ib = R0 & 2047;
#pragma unroll
  for (int nf = 0; nf < 8; ++nf) {
    acc = (f32x4){0.f, 0.f, 0.f, 0.f};
#pragma unroll
    for (int ks = 0; ks < 4; ++ks) {
      int c = ks * 4 + q;
      int nr = nf * 16 + lr;
      bf16x8 b = *(const bf16x8*)(w2T + (nr << 7) + ((c ^ (nr & 7)) << 3));
      acc = __builtin_amdgcn_mfma_f32_16x16x32_bf16(a2[ks], b, acc, 0, 0, 0);
    }
    float bias = gb2[nf * 16 + lr];
    u16x4 pk;
#pragma unroll
    for (int r = 0; r < 4; ++r) pk[r] = f2bf(acc[r] + bias);
    *(u16x4*)(gxT + (size_t)(batch * 128 + nf * 16 + lr) * 2048 + ib + w * 16 + q * 4) = pk;
  }
}

// ---------------- k_main: fused einsum + self-MLP, double-buffered ----------------
__global__ __launch_bounds__(256) void k_main(
    const float* __restrict__ edge,
    const unsigned short* __restrict__ gxT,
    const float* __restrict__ x,
    const float* __restrict__ fw1,
    const float* __restrict__ fb1,
    const float* __restrict__ fw2,
    const float* __restrict__ fb2,
    float* __restrict__ out)
{
  // eT[jj 0..31][ii 0..63]: stride 72 shorts, chunk swizzle (ii>>3)^(jj>>3):
  //   short addr = jj*72 + (((ii>>3)^(jj>>3))<<3) + (ii&7)
  //   pair-packed b32 writes: 32 banks x 2-way (free); b128 reads balanced.
  // bT[h 0..127][ii 0..63]: tight XOR: addr = h*64 + (((ii>>3)^(h&7))<<3) + (ii&7)
  __shared__ short eT[2][32 * 72];   // 9 KB
  __shared__ short bT[2][128 * 64];  // 32 KB
  __shared__ short xs[32 * 64];      // 4 KB  (epilogue)
  __shared__ short w1T[64 * 64];     // 8 KB  (epilogue)
  __shared__ short h1s[32 * 64];     // 4 KB  (epilogue)  -> 57 KB, 2 blocks/CU

  const int t = threadIdx.x;
  const int batch = blockIdx.x & 7;   // XCD-pinned: each XCD handles one batch (gx 512 KB L2-resident)
  const int j0 = (blockIdx.x >> 3) * 32;

  const int w = t >> 6, l = t & 63;
  const int wm = w & 1, wn = w >> 1;
  const int lr = l & 15, q = l >> 4;

  // loader roles: edge -> i-pair p (i=2p,2p+1), j-quad cq (j=4cq..4cq+3)
  const int p  = t >> 3;   // 0..31
  const int cq = t & 7;    // 0..7
  // gx -> h row g_hh + qq*32, i-chunk g_ci*8
  const int g_hh = t >> 3; // 0..31
  const int g_ci = t & 7;  // 0..7

  const float* ep = edge + (size_t)batch * 2048 * 2048 + (size_t)(2 * p) * 2048 + j0 + 4 * cq;
  const unsigned short* gp = gxT + (size_t)batch * 128 * 2048 + (size_t)g_hh * 2048 + g_ci * 8;

  f32x4 er0, er1;
  u16x8 gr[4];

  // tile 0 -> regs
  er0 = *(const f32x4*)ep;
  er1 = *(const f32x4*)(ep + 2048);
#pragma unroll
  for (int qq = 0; qq < 4; ++qq) gr[qq] = *(const u16x8*)(gp + (size_t)qq * 32 * 2048);

  f32x4 acc[4];
#pragma unroll
  for (int nf = 0; nf < 4; ++nf) acc[nf] = (f32x4){0.f, 0.f, 0.f, 0.f};

  // store tile 0 -> buf 0
#pragma unroll
  for (int u = 0; u < 4; ++u) {
    int j = 4 * cq + u;
    unsigned int pk = (unsigned int)f2bf(er0[u]) | ((unsigned int)f2bf(er1[u]) << 16);
    *(unsigned int*)(&eT[0][j * 72 + (((p >> 2) ^ (j >> 3)) << 3) + ((p & 3) << 1)]) = pk;
  }
#pragma unroll
  for (int qq = 0; qq < 4; ++qq) {
    int r = qq * 32 + g_hh;
    *(u16x8*)(&bT[0][(r << 6) + ((g_ci ^ (r & 7)) << 3)]) = gr[qq];
  }
  // tile 1 -> regs (in flight across barrier)
  ep += 64 * 2048; gp += 64;
  er0 = *(const f32x4*)ep;
  er1 = *(const f32x4*)(ep + 2048);
#pragma unroll
  for (int qq = 0; qq < 4; ++qq) gr[qq] = *(const u16x8*)(gp + (size_t)qq * 32 * 2048);
  __syncthreads();

  for (int kk = 0; kk < 32; ++kk) {
    const int cur = kk & 1;
    if (kk < 31) {
      const int nxt = cur ^ 1;
      // store tile kk+1 from regs (pair-packed b32, conflict-free)
#pragma unroll
      for (int u = 0; u < 4; ++u) {
        int j = 4 * cq + u;
        unsigned int pk = (unsigned int)f2bf(er0[u]) | ((unsigned int)f2bf(er1[u]) << 16);
        *(unsigned int*)(&eT[nxt][j * 72 + (((p >> 2) ^ (j >> 3)) << 3) + ((p & 3) << 1)]) = pk;
      }
#pragma unroll
      for (int qq = 0; qq < 4; ++qq) {
        int r = qq * 32 + g_hh;
        *(u16x8*)(&bT[nxt][(r << 6) + ((g_ci ^ (r & 7)) << 3)]) = gr[qq];
      }
      if (kk < 30) {  // issue load tile kk+2
        ep += 64 * 2048; gp += 64;
        er0 = *(const f32x4*)ep;
        er1 = *(const f32x4*)(ep + 2048);
#pragma unroll
        for (int qq = 0; qq < 4; ++qq) gr[qq] = *(const u16x8*)(gp + (size_t)qq * 32 * 2048);
      }
    }

    // MFMA from buf[cur]
#pragma unroll
    for (int ks = 0; ks < 2; ++ks) {
      const int c = ks * 4 + q;
      const int jj = wm * 16 + lr;
      bf16x8 a = *(const bf16x8*)(&eT[cur][jj * 72 + ((c ^ (jj >> 3)) << 3)]);
      bf16x8 b[4];
#pragma unroll
      for (int nf = 0; nf < 4; ++nf) {
        int h = wn * 64 + nf * 16 + lr;
        b[nf] = *(const bf16x8*)(&bT[cur][(h << 6) + ((c ^ (h & 7)) << 3)]);
      }
#pragma unroll
      for (int nf = 0; nf < 4; ++nf)
        acc[nf] = __builtin_amdgcn_mfma_f32_16x16x32_bf16(a, b[nf], acc[nf], 0, 0, 0);
    }
    __syncthreads();  // read(buf cur) before next iter's write(buf cur)
  }

  // ---- fused self-MLP epilogue: acc += relu(x_j @ fw1 + b1) @ fw2 + b2 ----
  for (int idx = t; idx < 64 * 64; idx += 256) {
    int k = idx >> 6, n = idx & 63;  // fw1[k][n]
    w1T[(n << 6) + (((k >> 3) ^ (n & 7)) << 3) + (k & 7)] = (short)f2bf(fw1[idx]);
  }
  for (int idx = t; idx < 64 * 128; idx += 256) {
    int k = idx >> 7, n = idx & 127;  // fw2[k][n] -> bT[0] reused as fw2T
    bT[0][(n << 6) + (((k >> 3) ^ (n & 7)) << 3) + (k & 7)] = (short)f2bf(fw2[idx]);
  }
  for (int s = t; s < 32 * 16; s += 256) {
    int row = s >> 4, c4 = s & 15;
    f32x4 v = *(const f32x4*)(x + (size_t)(batch * 2048 + j0 + row) * 64 + c4 * 4);
    u16x4 pk;
#pragma unroll
    for (int r = 0; r < 4; ++r) pk[r] = f2bf(v[r]);
    *(u16x4*)(xs + (row << 6) + (((c4 >> 1) ^ (row & 7)) << 3) + ((c4 & 1) << 2)) = pk;
  }
  __syncthreads();

  const int mrow = wm * 16 + lr;
  if (wn == 0) {  // layer 1: two waves compute hidden[32][64]
    bf16x8 a1[2];
#pragma unroll
    for (int ks = 0; ks < 2; ++ks) {
      int c = ks * 4 + q;
      a1[ks] = *(const bf16x8*)(xs + (mrow << 6) + ((c ^ (mrow & 7)) << 3));
    }
#pragma unroll
    for (int nf = 0; nf < 4; ++nf) {
      f32x4 h = (f32x4){0.f, 0.f, 0.f, 0.f};
#pragma unroll
      for (int ks = 0; ks < 2; ++ks) {
        int c = ks * 4 + q;
        int nr = nf * 16 + lr;
        bf16x8 b = *(const bf16x8*)(w1T + (nr << 6) + ((c ^ (nr & 7)) << 3));
        h = __builtin_amdgcn_mfma_f32_16x16x32_bf16(a1[ks], b, h, 0, 0, 0);
      }
      float bias = fb1[nf * 16 + lr];
#pragma unroll
      for (int r = 0; r < 4; ++r) {
        float v = h[r] + bias;
        v = v > 0.f ? v : 0.f;
        int row = wm * 16 + q * 4 + r, n = nf * 16 + lr;
        h1s[(row << 6) + (((n >> 3) ^ (row & 7)) << 3) + (n & 7)] = (short)f2bf(v);
      }
    }
  }
  __syncthreads();

  // layer 2: all waves, accumulate straight into einsum acc
  bf16x8 a2[2];
#pragma unroll
  for (int ks = 0; ks < 2; ++ks) {
    int c = ks * 4 + q;
    a2[ks] = *(const bf16x8*)(h1s + (mrow << 6) + ((c ^ (mrow & 7)) << 3));
  }
#pragma unroll
  for (int nf = 0; nf < 4; ++nf) {
    int h = wn * 64 + nf * 16 + lr;
#pragma unroll
    for (int ks = 0; ks < 2; ++ks) {
      int c = ks * 4 + q;
      bf16x8 b = *(const bf16x8*)(&bT[0][(h << 6) + ((c ^ (h & 7)) << 3)]);
      acc[nf] = __builtin_amdgcn_mfma_f32_16x16x32_bf16(a2[ks], b, acc[nf], 0, 0, 0);
    }
    float bias = fb2[h];
#pragma unroll
    for (int r = 0; r < 4; ++r) {
      size_t o = ((size_t)batch * 2048 + j0 + wm * 16 + q * 4 + r) * 128 + h;
      out[o] = acc[nf][r] + bias;
    }
  }
}

extern "C" void kernel_launch(void* const* d_in, const int* in_sizes, int n_in,
                              void* d_out, int out_size, void* d_ws, size_t ws_size,
                              hipStream_t stream) {
  const float* x    = (const float*)d_in[0];
  const float* edge = (const float*)d_in[1];
  const float* fw1  = (const float*)d_in[2];
  const float* fb1  = (const float*)d_in[3];
  const float* fw2  = (const float*)d_in[4];
  const float* fb2  = (const float*)d_in[5];
  const float* gw1  = (const float*)d_in[6];
  const float* gb1  = (const float*)d_in[7];
  const float* gw2  = (const float*)d_in[8];
  const float* gb2  = (const float*)d_in[9];
  float* out = (float*)d_out;

  unsigned short* gxT = (unsigned short*)d_ws;  // [8][128][2048] bf16, 4 MB

  hipLaunchKernelGGL(k_gx, dim3(256), dim3(256), 0, stream, x, gw1, gb1, gw2, gb2, gxT);
  hipLaunchKernelGGL(k_main, dim3(512), dim3(256), 0, stream, edge, gxT, x,
                     fw1, fb1, fw2, fb2, out);
}